// Round 4
// baseline (376.947 us; speedup 1.0000x reference)
//
#include <hip/hip_runtime.h>
#include <array>

namespace {

constexpr int NPAIRS = 40000;
constexpr long NF = (long)NPAIRS * 128;  // elements per (l,m) plane

// ---------------------------------------------------------------------------
// Compile-time enumeration of nonzero CG terms (symmetrized):
// out[o] += (cg[o,a,b]+cg[o,b,a]) * x[a] * y[b]
// ---------------------------------------------------------------------------
struct Term {
  int o, a, b;
};

constexpr int count_terms() {
  int idx = 0;
  for (int o = 0; o < 15; ++o) {
    const int l3 = o / 5, m3 = o % 5 - 2;
    if (m3 < -l3 || m3 > l3) continue;
    for (int l1 = 0; l1 < 3; ++l1)
      for (int l2 = 0; l2 < 3; ++l2) {
        const int ld = l1 > l2 ? l1 - l2 : l2 - l1;
        if (l3 < ld || l3 > l1 + l2) continue;
        const int mlo = (-l1 > m3 - l2) ? -l1 : m3 - l2;
        const int mhi = (l1 < m3 + l2) ? l1 : m3 + l2;
        for (int m1 = mlo; m1 <= mhi; ++m1) ++idx;
      }
  }
  return idx;
}
constexpr int NTERMS = count_terms();
static_assert(NTERMS == 117, "term count");

constexpr std::array<Term, NTERMS> make_terms() {
  std::array<Term, NTERMS> t{};
  int idx = 0;
  for (int o = 0; o < 15; ++o) {
    const int l3 = o / 5, m3 = o % 5 - 2;
    if (m3 < -l3 || m3 > l3) continue;
    for (int l1 = 0; l1 < 3; ++l1)
      for (int l2 = 0; l2 < 3; ++l2) {
        const int ld = l1 > l2 ? l1 - l2 : l2 - l1;
        if (l3 < ld || l3 > l1 + l2) continue;
        const int mlo = (-l1 > m3 - l2) ? -l1 : m3 - l2;
        const int mhi = (l1 < m3 + l2) ? l1 : m3 + l2;
        for (int m1 = mlo; m1 <= mhi; ++m1) {
          t[idx].o = o;
          t[idx].a = l1 * 5 + m1 + 2;
          t[idx].b = l2 * 5 + (m3 - m1) + 2;
          ++idx;
        }
      }
  }
  return t;
}
constexpr auto TERMS = make_terms();

// Plane -> dense index for the 9 "valid" (l,m) slots; -1 for the 6 zero slots.
// The same 9-slot set applies to outputs (o), and to inputs (a, b).
constexpr std::array<int, 15> make_acc_idx() {
  std::array<int, 15> m{};
  for (int o = 0; o < 15; ++o) m[o] = -1;
  int q = 0;
  for (int o = 0; o < 15; ++o) {
    const int l3 = o / 5, m3 = o % 5 - 2;
    if (m3 >= -l3 && m3 <= l3) m[o] = q++;
  }
  return m;
}
constexpr auto ACC_IDX = make_acc_idx();

constexpr std::array<int, 9> make_used() {
  std::array<int, 9> u{};
  int q = 0;
  for (int o = 0; o < 15; ++o)
    if (ACC_IDX[o] >= 0) u[q++] = o;
  return u;
}
constexpr auto USED = make_used();

// ---------------------------------------------------------------------------
// Compile-time Hermite recurrence coefficients:
// h_{k+1} = sqrt(2/(k+1)) g h_k - sqrt(k/(k+1)) h_{k-1}
// ---------------------------------------------------------------------------
constexpr double csqrt(double x) {
  double g = x > 1.0 ? x : 1.0;
  for (int i = 0; i < 64; ++i) g = 0.5 * (g + x / g);
  return g;
}
constexpr std::array<float, 128> make_c1() {
  std::array<float, 128> a{};
  for (int k = 0; k < 128; ++k) a[k] = (float)csqrt(2.0 / (k + 1));
  return a;
}
constexpr std::array<float, 128> make_c2() {
  std::array<float, 128> a{};
  for (int k = 0; k < 128; ++k) a[k] = (float)csqrt((double)k / (k + 1));
  return a;
}
constexpr auto C1 = make_c1();
constexpr auto C2 = make_c2();

// ---------------------------------------------------------------------------
// Fused kernel. Block = 256 threads = 512 contiguous elements = 4 n x 128 f.
// Each thread owns a float2 (one n, features f0=2u, f0+1).
// Phase 1: issue the 18 used-plane x/y loads (latency hides under phase 2).
// Phase 2: s = (w1 h)(w2 h) via in-register Hermite recurrence fused with two
//          dot products; w1/w2 staged per-k-chunk transposed in LDS.
// Phase 3: 117-term CG contraction, scale by s, write all 15 planes.
// ---------------------------------------------------------------------------
__global__ __attribute__((amdgpu_waves_per_eu(4, 4)))
__launch_bounds__(256) void fused_kernel(const float* __restrict__ x,
                                         const float* __restrict__ y,
                                         const float* __restrict__ g,
                                         const float* __restrict__ w1,
                                         const float* __restrict__ w2,
                                         const float* __restrict__ cg,
                                         float* __restrict__ out) {
  __shared__ float wt1[16][132];  // w1 chunk transposed [k_local][f]
  __shared__ float wt2[16][132];
  __shared__ float d2s[NTERMS];

  const int tid = threadIdx.x;
  if (tid < NTERMS) {
    const Term tm = TERMS[tid];
    d2s[tid] = cg[(tm.o * 15 + tm.a) * 15 + tm.b] + cg[(tm.o * 15 + tm.b) * 15 + tm.a];
  }

  const int u = tid & 63;   // f0 = 2u
  const int nl = tid >> 6;  // 0..3
  const long n = (long)blockIdx.x * 4 + nl;
  const long off = n * 128 + 2 * u;

  // Phase 1: early-issue used-plane loads.
  float2 xv[9], yv[9];
#pragma unroll
  for (int q = 0; q < 9; ++q) xv[q] = *(const float2*)(x + (long)USED[q] * NF + off);
#pragma unroll
  for (int q = 0; q < 9; ++q) yv[q] = *(const float2*)(y + (long)USED[q] * NF + off);

  // Phase 2: fused Hermite recurrence + dot products.
  const float gv = g[n];
  float hprev = 0.f;
  float hcur = 0.75112554446494248286f * expf(-0.5f * gv * gv);  // h_0
  float2 dot1 = make_float2(0.f, 0.f);
  float2 dot2 = make_float2(0.f, 0.f);

  const int fr = tid >> 1;    // staging row f = 0..127
  const int half = tid & 1;   // k-half within chunk

#pragma unroll
  for (int kc = 0; kc < 8; ++kc) {
    const float* wp1 = w1 + fr * 128 + kc * 16 + half * 8;
    const float* wp2 = w2 + fr * 128 + kc * 16 + half * 8;
    const float4 a0 = *(const float4*)(wp1);
    const float4 a1 = *(const float4*)(wp1 + 4);
    const float4 b0 = *(const float4*)(wp2);
    const float4 b1 = *(const float4*)(wp2 + 4);
    __syncthreads();  // previous chunk fully consumed (no-op cost on kc=0)
    const int k0 = half * 8;
    wt1[k0 + 0][fr] = a0.x;
    wt1[k0 + 1][fr] = a0.y;
    wt1[k0 + 2][fr] = a0.z;
    wt1[k0 + 3][fr] = a0.w;
    wt1[k0 + 4][fr] = a1.x;
    wt1[k0 + 5][fr] = a1.y;
    wt1[k0 + 6][fr] = a1.z;
    wt1[k0 + 7][fr] = a1.w;
    wt2[k0 + 0][fr] = b0.x;
    wt2[k0 + 1][fr] = b0.y;
    wt2[k0 + 2][fr] = b0.z;
    wt2[k0 + 3][fr] = b0.w;
    wt2[k0 + 4][fr] = b1.x;
    wt2[k0 + 5][fr] = b1.y;
    wt2[k0 + 6][fr] = b1.z;
    wt2[k0 + 7][fr] = b1.w;
    __syncthreads();

#pragma unroll
    for (int kk = 0; kk < 16; ++kk) {
      const int k = kc * 16 + kk;
      const float2 wa = *(const float2*)&wt1[kk][2 * u];
      const float2 wb = *(const float2*)&wt2[kk][2 * u];
      dot1.x = fmaf(wa.x, hcur, dot1.x);
      dot1.y = fmaf(wa.y, hcur, dot1.y);
      dot2.x = fmaf(wb.x, hcur, dot2.x);
      dot2.y = fmaf(wb.y, hcur, dot2.y);
      const float hnext = C1[k] * gv * hcur - C2[k] * hprev;
      hprev = hcur;
      hcur = hnext;
    }
  }

  const float2 sv = make_float2(dot1.x * dot2.x, dot1.y * dot2.y);

  // Phase 3: CG contraction over dense 9-plane registers.
  float accx[9], accy[9];
#pragma unroll
  for (int q = 0; q < 9; ++q) {
    accx[q] = 0.f;
    accy[q] = 0.f;
  }

#pragma unroll
  for (int t = 0; t < NTERMS; ++t) {
    const int qo = ACC_IDX[TERMS[t].o];
    const int qa = ACC_IDX[TERMS[t].a];
    const int qb = ACC_IDX[TERMS[t].b];
    const float c = d2s[t];
    accx[qo] = fmaf(c, xv[qa].x * yv[qb].x, accx[qo]);
    accy[qo] = fmaf(c, xv[qa].y * yv[qb].y, accy[qo]);
  }

#pragma unroll
  for (int o = 0; o < 15; ++o) {
    const int q = ACC_IDX[o];
    float2 r;
    if (q >= 0) {
      r.x = accx[q] * sv.x;
      r.y = accy[q] * sv.y;
    } else {
      r.x = 0.f;
      r.y = 0.f;
    }
    *(float2*)(out + (long)o * NF + off) = r;
  }
}

}  // namespace

extern "C" void kernel_launch(void* const* d_in, const int* in_sizes, int n_in,
                              void* d_out, int out_size, void* d_ws, size_t ws_size,
                              hipStream_t stream) {
  const float* x = (const float*)d_in[0];
  const float* y = (const float*)d_in[1];
  const float* g = (const float*)d_in[2];
  const float* w1 = (const float*)d_in[3];
  const float* w2 = (const float*)d_in[4];
  const float* cg = (const float*)d_in[5];
  float* out = (float*)d_out;

  fused_kernel<<<10000, 256, 0, stream>>>(x, y, g, w1, w2, cg, out);
}

// Round 5
// 238.061 us; speedup vs baseline: 1.5834x; 1.5834x over previous
//
#include <hip/hip_runtime.h>
#include <array>

namespace {

constexpr int NPAIRS = 40000;
constexpr long NF = (long)NPAIRS * 128;  // elements per (l,m) plane

// ---------------------------------------------------------------------------
// Compile-time enumeration of nonzero CG terms (symmetrized):
// out[o] += (cg[o,a,b]+cg[o,b,a]) * x[a] * y[b]
// ---------------------------------------------------------------------------
struct Term {
  int o, a, b;
};

constexpr int count_terms() {
  int idx = 0;
  for (int o = 0; o < 15; ++o) {
    const int l3 = o / 5, m3 = o % 5 - 2;
    if (m3 < -l3 || m3 > l3) continue;
    for (int l1 = 0; l1 < 3; ++l1)
      for (int l2 = 0; l2 < 3; ++l2) {
        const int ld = l1 > l2 ? l1 - l2 : l2 - l1;
        if (l3 < ld || l3 > l1 + l2) continue;
        const int mlo = (-l1 > m3 - l2) ? -l1 : m3 - l2;
        const int mhi = (l1 < m3 + l2) ? l1 : m3 + l2;
        for (int m1 = mlo; m1 <= mhi; ++m1) ++idx;
      }
  }
  return idx;
}
constexpr int NTERMS = count_terms();
static_assert(NTERMS == 117, "term count");

constexpr std::array<Term, NTERMS> make_terms() {
  std::array<Term, NTERMS> t{};
  int idx = 0;
  for (int o = 0; o < 15; ++o) {
    const int l3 = o / 5, m3 = o % 5 - 2;
    if (m3 < -l3 || m3 > l3) continue;
    for (int l1 = 0; l1 < 3; ++l1)
      for (int l2 = 0; l2 < 3; ++l2) {
        const int ld = l1 > l2 ? l1 - l2 : l2 - l1;
        if (l3 < ld || l3 > l1 + l2) continue;
        const int mlo = (-l1 > m3 - l2) ? -l1 : m3 - l2;
        const int mhi = (l1 < m3 + l2) ? l1 : m3 + l2;
        for (int m1 = mlo; m1 <= mhi; ++m1) {
          t[idx].o = o;
          t[idx].a = l1 * 5 + m1 + 2;
          t[idx].b = l2 * 5 + (m3 - m1) + 2;
          ++idx;
        }
      }
  }
  return t;
}
constexpr auto TERMS = make_terms();

// Plane -> dense index for the 9 valid (l,m) slots; -1 for the 6 zero slots.
constexpr std::array<int, 15> make_acc_idx() {
  std::array<int, 15> m{};
  for (int o = 0; o < 15; ++o) m[o] = -1;
  int q = 0;
  for (int o = 0; o < 15; ++o) {
    const int l3 = o / 5, m3 = o % 5 - 2;
    if (m3 >= -l3 && m3 <= l3) m[o] = q++;
  }
  return m;
}
constexpr auto ACC_IDX = make_acc_idx();

constexpr std::array<int, 9> make_used() {
  std::array<int, 9> u{};
  int q = 0;
  for (int o = 0; o < 15; ++o)
    if (ACC_IDX[o] >= 0) u[q++] = o;
  return u;
}
constexpr auto USED = make_used();

// ---------------------------------------------------------------------------
// Kernel A: s[n,f] = (sum_k w1[f,k] h[n,k]) * (sum_k w2[f,k] h[n,k])
// Unchanged from R3 (~30 us). Output -> plane 0 of `out` (a zero plane).
// ---------------------------------------------------------------------------
__global__ __launch_bounds__(256, 4) void s_kernel(const float* __restrict__ g,
                                                   const float* __restrict__ w1,
                                                   const float* __restrict__ w2,
                                                   float* __restrict__ s_out) {
  __shared__ float ht[128][32];
  __shared__ float wt1[16][132];
  __shared__ float wt2[16][132];

  const int tid = threadIdx.x;
  const int blk = blockIdx.x;

  if (tid < 32) {
    const float gv = g[blk * 32 + tid];
    float hkm1 = 0.75112554446494248286f * expf(-0.5f * gv * gv);
    float hk = 1.41421356237309504880f * gv * hkm1;
    ht[0][tid] = hkm1;
    ht[1][tid] = hk;
#pragma unroll 1
    for (int k = 1; k <= 126; ++k) {
      const float kf = (float)k;
      const float hkp1 =
          sqrtf(2.0f / (kf + 1.0f)) * gv * hk - sqrtf(kf / (kf + 1.0f)) * hkm1;
      ht[k + 1][tid] = hkp1;
      hkm1 = hk;
      hk = hkp1;
    }
  }

  const int fg = tid & 31;
  const int ng = tid >> 5;

  float acc1[4][4];
  float acc2[4][4];
#pragma unroll
  for (int i = 0; i < 4; ++i)
#pragma unroll
    for (int j = 0; j < 4; ++j) {
      acc1[i][j] = 0.f;
      acc2[i][j] = 0.f;
    }

  for (int kc = 0; kc < 8; ++kc) {
#pragma unroll
    for (int it = 0; it < 2; ++it) {
      const int lin = tid + it * 256;
      const int f = lin >> 2;
      const int kq = lin & 3;
      const float4 v1 = *(const float4*)(w1 + f * 128 + kc * 16 + kq * 4);
      const float4 v2 = *(const float4*)(w2 + f * 128 + kc * 16 + kq * 4);
      wt1[kq * 4 + 0][f] = v1.x;
      wt1[kq * 4 + 1][f] = v1.y;
      wt1[kq * 4 + 2][f] = v1.z;
      wt1[kq * 4 + 3][f] = v1.w;
      wt2[kq * 4 + 0][f] = v2.x;
      wt2[kq * 4 + 1][f] = v2.y;
      wt2[kq * 4 + 2][f] = v2.z;
      wt2[kq * 4 + 3][f] = v2.w;
    }
    __syncthreads();

#pragma unroll
    for (int kk = 0; kk < 16; ++kk) {
      const float4 wv1 = *(const float4*)&wt1[kk][fg * 4];
      const float4 wv2 = *(const float4*)&wt2[kk][fg * 4];
      const float4 ha = *(const float4*)&ht[kc * 16 + kk][ng * 4];
      const float hv[4] = {ha.x, ha.y, ha.z, ha.w};
#pragma unroll
      for (int i = 0; i < 4; ++i) {
        acc1[i][0] = fmaf(hv[i], wv1.x, acc1[i][0]);
        acc1[i][1] = fmaf(hv[i], wv1.y, acc1[i][1]);
        acc1[i][2] = fmaf(hv[i], wv1.z, acc1[i][2]);
        acc1[i][3] = fmaf(hv[i], wv1.w, acc1[i][3]);
        acc2[i][0] = fmaf(hv[i], wv2.x, acc2[i][0]);
        acc2[i][1] = fmaf(hv[i], wv2.y, acc2[i][1]);
        acc2[i][2] = fmaf(hv[i], wv2.z, acc2[i][2]);
        acc2[i][3] = fmaf(hv[i], wv2.w, acc2[i][3]);
      }
    }
    __syncthreads();
  }

#pragma unroll
  for (int i = 0; i < 4; ++i) {
    const long n = (long)blk * 32 + ng * 4 + i;
    float4 sv;
    sv.x = acc1[i][0] * acc2[i][0];
    sv.y = acc1[i][1] * acc2[i][1];
    sv.z = acc1[i][2] * acc2[i][2];
    sv.w = acc1[i][3] * acc2[i][3];
    *(float4*)(s_out + n * 128 + fg * 4) = sv;
  }
}

// ---------------------------------------------------------------------------
// Kernel B: out[o,n,f] = s[n,f] * sum_t d2[t] x[a_t,n,f] y[b_t,n,f]
// float4 per thread (16 B/lane). Only the 9 used planes of x/y are read.
// sched_barrier(0) pins all 19 loads above the compute -> full MLP batch.
// s lives in plane 0 of `out` (a zero output plane); read before overwrite.
// ---------------------------------------------------------------------------
__global__ __attribute__((amdgpu_waves_per_eu(3, 4)))
__launch_bounds__(256) void tp_kernel(const float* __restrict__ x,
                                      const float* __restrict__ y,
                                      const float* __restrict__ cg,
                                      float* __restrict__ out) {
  __shared__ float d2s[NTERMS];
  const int tid = threadIdx.x;
  if (tid < NTERMS) {
    const Term tm = TERMS[tid];
    d2s[tid] = cg[(tm.o * 15 + tm.a) * 15 + tm.b] + cg[(tm.o * 15 + tm.b) * 15 + tm.a];
  }
  __syncthreads();

  const long off = (long)blockIdx.x * 1024 + tid * 4;  // float4-aligned element offset

  float4 xv[9], yv[9];
#pragma unroll
  for (int q = 0; q < 9; ++q) xv[q] = *(const float4*)(x + (long)USED[q] * NF + off);
#pragma unroll
  for (int q = 0; q < 9; ++q) yv[q] = *(const float4*)(y + (long)USED[q] * NF + off);
  const float4 sv = *(const float4*)(out + off);  // s from plane 0 (own offset)
  __builtin_amdgcn_sched_barrier(0);  // keep all loads issued as one batch

  float4 acc[9];
#pragma unroll
  for (int q = 0; q < 9; ++q) acc[q] = make_float4(0.f, 0.f, 0.f, 0.f);

#pragma unroll
  for (int t = 0; t < NTERMS; ++t) {
    const int qo = ACC_IDX[TERMS[t].o];
    const int qa = ACC_IDX[TERMS[t].a];
    const int qb = ACC_IDX[TERMS[t].b];
    const float c = d2s[t];
    acc[qo].x = fmaf(c, xv[qa].x * yv[qb].x, acc[qo].x);
    acc[qo].y = fmaf(c, xv[qa].y * yv[qb].y, acc[qo].y);
    acc[qo].z = fmaf(c, xv[qa].z * yv[qb].z, acc[qo].z);
    acc[qo].w = fmaf(c, xv[qa].w * yv[qb].w, acc[qo].w);
  }

#pragma unroll
  for (int o = 0; o < 15; ++o) {
    const int q = ACC_IDX[o];
    float4 r;
    if (q >= 0) {
      r.x = acc[q].x * sv.x;
      r.y = acc[q].y * sv.y;
      r.z = acc[q].z * sv.z;
      r.w = acc[q].w * sv.w;
    } else {
      r = make_float4(0.f, 0.f, 0.f, 0.f);
    }
    *(float4*)(out + (long)o * NF + off) = r;
  }
}

}  // namespace

extern "C" void kernel_launch(void* const* d_in, const int* in_sizes, int n_in,
                              void* d_out, int out_size, void* d_ws, size_t ws_size,
                              hipStream_t stream) {
  const float* x = (const float*)d_in[0];
  const float* y = (const float*)d_in[1];
  const float* g = (const float*)d_in[2];
  const float* w1 = (const float*)d_in[3];
  const float* w2 = (const float*)d_in[4];
  const float* cg = (const float*)d_in[5];
  float* out = (float*)d_out;

  // Pass 1: s[n,f] -> plane 0 of out (a guaranteed-zero output plane).
  s_kernel<<<1250, 256, 0, stream>>>(g, w1, w2, out);
  // Pass 2: streaming tensor-product contraction; writes all 15 planes.
  tp_kernel<<<5000, 256, 0, stream>>>(x, y, cg, out);
}

// Round 6
// 220.869 us; speedup vs baseline: 1.7067x; 1.0778x over previous
//
#include <hip/hip_runtime.h>
#include <array>

namespace {

constexpr int NPAIRS = 40000;
constexpr long NF = (long)NPAIRS * 128;  // elements per (l,m) plane

constexpr int CHUNK = 1024;              // elements per plane per chunk (4 KB)
constexpr int NCHUNKS = (int)(NF / CHUNK);  // 5000
constexpr int BLOCKS = 250;
constexpr int CPB = NCHUNKS / BLOCKS;    // 20 chunks per block

// ---------------------------------------------------------------------------
// Compile-time enumeration of nonzero CG terms (symmetrized):
// out[o] += (cg[o,a,b]+cg[o,b,a]) * x[a] * y[b]  over all ordered pairs (a,b).
// ---------------------------------------------------------------------------
struct Term {
  int o, a, b;
};

constexpr int count_terms() {
  int idx = 0;
  for (int o = 0; o < 15; ++o) {
    const int l3 = o / 5, m3 = o % 5 - 2;
    if (m3 < -l3 || m3 > l3) continue;
    for (int l1 = 0; l1 < 3; ++l1)
      for (int l2 = 0; l2 < 3; ++l2) {
        const int ld = l1 > l2 ? l1 - l2 : l2 - l1;
        if (l3 < ld || l3 > l1 + l2) continue;
        const int mlo = (-l1 > m3 - l2) ? -l1 : m3 - l2;
        const int mhi = (l1 < m3 + l2) ? l1 : m3 + l2;
        for (int m1 = mlo; m1 <= mhi; ++m1) ++idx;
      }
  }
  return idx;
}
constexpr int NTERMS = count_terms();
static_assert(NTERMS == 117, "term count");

constexpr std::array<Term, NTERMS> make_terms() {
  std::array<Term, NTERMS> t{};
  int idx = 0;
  for (int o = 0; o < 15; ++o) {
    const int l3 = o / 5, m3 = o % 5 - 2;
    if (m3 < -l3 || m3 > l3) continue;
    for (int l1 = 0; l1 < 3; ++l1)
      for (int l2 = 0; l2 < 3; ++l2) {
        const int ld = l1 > l2 ? l1 - l2 : l2 - l1;
        if (l3 < ld || l3 > l1 + l2) continue;
        const int mlo = (-l1 > m3 - l2) ? -l1 : m3 - l2;
        const int mhi = (l1 < m3 + l2) ? l1 : m3 + l2;
        for (int m1 = mlo; m1 <= mhi; ++m1) {
          t[idx].o = o;
          t[idx].a = l1 * 5 + m1 + 2;
          t[idx].b = l2 * 5 + (m3 - m1) + 2;
          ++idx;
        }
      }
  }
  return t;
}
constexpr auto TERMS = make_terms();

// Plane -> dense index for the 9 valid (l,m) slots; -1 for the 6 zero slots.
constexpr std::array<int, 15> make_acc_idx() {
  std::array<int, 15> m{};
  for (int o = 0; o < 15; ++o) m[o] = -1;
  int q = 0;
  for (int o = 0; o < 15; ++o) {
    const int l3 = o / 5, m3 = o % 5 - 2;
    if (m3 >= -l3 && m3 <= l3) m[o] = q++;
  }
  return m;
}
constexpr auto ACC_IDX = make_acc_idx();

constexpr std::array<int, 9> make_used() {
  std::array<int, 9> u{};
  int q = 0;
  for (int o = 0; o < 15; ++o)
    if (ACC_IDX[o] >= 0) u[q++] = o;
  return u;
}
constexpr auto USED = make_used();

// Async 16B global -> LDS copy. LDS dest is wave-uniform base + lane*16;
// global src is per-lane.
__device__ __forceinline__ void dma16(const float* gsrc, float* ldst) {
  __builtin_amdgcn_global_load_lds(
      (const __attribute__((address_space(1))) void*)gsrc,
      (__attribute__((address_space(3))) void*)ldst, 16, 0, 0);
}

// ---------------------------------------------------------------------------
// Kernel A: s[n,f] = (sum_k w1[f,k] h[n,k]) * (sum_k w2[f,k] h[n,k])
// Unchanged (proven ~30 us). Output -> plane 0 of `out` (a zero plane).
// ---------------------------------------------------------------------------
__global__ __launch_bounds__(256, 4) void s_kernel(const float* __restrict__ g,
                                                   const float* __restrict__ w1,
                                                   const float* __restrict__ w2,
                                                   float* __restrict__ s_out) {
  __shared__ float ht[128][32];
  __shared__ float wt1[16][132];
  __shared__ float wt2[16][132];

  const int tid = threadIdx.x;
  const int blk = blockIdx.x;

  if (tid < 32) {
    const float gv = g[blk * 32 + tid];
    float hkm1 = 0.75112554446494248286f * expf(-0.5f * gv * gv);
    float hk = 1.41421356237309504880f * gv * hkm1;
    ht[0][tid] = hkm1;
    ht[1][tid] = hk;
#pragma unroll 1
    for (int k = 1; k <= 126; ++k) {
      const float kf = (float)k;
      const float hkp1 =
          sqrtf(2.0f / (kf + 1.0f)) * gv * hk - sqrtf(kf / (kf + 1.0f)) * hkm1;
      ht[k + 1][tid] = hkp1;
      hkm1 = hk;
      hk = hkp1;
    }
  }

  const int fg = tid & 31;
  const int ng = tid >> 5;

  float acc1[4][4];
  float acc2[4][4];
#pragma unroll
  for (int i = 0; i < 4; ++i)
#pragma unroll
    for (int j = 0; j < 4; ++j) {
      acc1[i][j] = 0.f;
      acc2[i][j] = 0.f;
    }

  for (int kc = 0; kc < 8; ++kc) {
#pragma unroll
    for (int it = 0; it < 2; ++it) {
      const int lin = tid + it * 256;
      const int f = lin >> 2;
      const int kq = lin & 3;
      const float4 v1 = *(const float4*)(w1 + f * 128 + kc * 16 + kq * 4);
      const float4 v2 = *(const float4*)(w2 + f * 128 + kc * 16 + kq * 4);
      wt1[kq * 4 + 0][f] = v1.x;
      wt1[kq * 4 + 1][f] = v1.y;
      wt1[kq * 4 + 2][f] = v1.z;
      wt1[kq * 4 + 3][f] = v1.w;
      wt2[kq * 4 + 0][f] = v2.x;
      wt2[kq * 4 + 1][f] = v2.y;
      wt2[kq * 4 + 2][f] = v2.z;
      wt2[kq * 4 + 3][f] = v2.w;
    }
    __syncthreads();

#pragma unroll
    for (int kk = 0; kk < 16; ++kk) {
      const float4 wv1 = *(const float4*)&wt1[kk][fg * 4];
      const float4 wv2 = *(const float4*)&wt2[kk][fg * 4];
      const float4 ha = *(const float4*)&ht[kc * 16 + kk][ng * 4];
      const float hv[4] = {ha.x, ha.y, ha.z, ha.w};
#pragma unroll
      for (int i = 0; i < 4; ++i) {
        acc1[i][0] = fmaf(hv[i], wv1.x, acc1[i][0]);
        acc1[i][1] = fmaf(hv[i], wv1.y, acc1[i][1]);
        acc1[i][2] = fmaf(hv[i], wv1.z, acc1[i][2]);
        acc1[i][3] = fmaf(hv[i], wv1.w, acc1[i][3]);
        acc2[i][0] = fmaf(hv[i], wv2.x, acc2[i][0]);
        acc2[i][1] = fmaf(hv[i], wv2.y, acc2[i][1]);
        acc2[i][2] = fmaf(hv[i], wv2.z, acc2[i][2]);
        acc2[i][3] = fmaf(hv[i], wv2.w, acc2[i][3]);
      }
    }
    __syncthreads();
  }

#pragma unroll
  for (int i = 0; i < 4; ++i) {
    const long n = (long)blk * 32 + ng * 4 + i;
    float4 sv;
    sv.x = acc1[i][0] * acc2[i][0];
    sv.y = acc1[i][1] * acc2[i][1];
    sv.z = acc1[i][2] * acc2[i][2];
    sv.w = acc1[i][3] * acc2[i][3];
    *(float4*)(s_out + n * 128 + fg * 4) = sv;
  }
}

// ---------------------------------------------------------------------------
// Kernel B: DMA-pipelined streaming contraction.
// 250 blocks (1/CU), 256 threads (4 waves), 144 KB dynamic LDS.
// Per chunk (1024 elem/plane): each wave DMAs its own 1 KB quarter of the
// 18 used x/y planes into LDS (double-buffered), waits with counted
// vmcnt(19) (never 0), computes 117 CG terms from its own LDS region,
// scales by reg-prefetched s, stores 15 output planes. No barriers in loop:
// waves are fully self-contained.
// ---------------------------------------------------------------------------
__global__ __attribute__((amdgpu_waves_per_eu(1, 2)))
__launch_bounds__(256) void tp_kernel(const float* __restrict__ x,
                                      const float* __restrict__ y,
                                      const float* __restrict__ cg,
                                      float* __restrict__ out) {
  extern __shared__ float smem[];            // [2][18*CHUNK] + d2s[NTERMS]
  float* d2s = smem + 2 * 18 * CHUNK;

  const int tid = threadIdx.x;
  if (tid < NTERMS) {
    const Term tm = TERMS[tid];
    d2s[tid] = cg[(tm.o * 15 + tm.a) * 15 + tm.b] + cg[(tm.o * 15 + tm.b) * 15 + tm.a];
  }
  __syncthreads();

  const int wv = tid >> 6;                   // wave id 0..3
  const int lane = tid & 63;
  const long base0 = (long)blockIdx.x * CPB * CHUNK;  // block's first element
  const long lsrc = wv * 256 + lane * 4;     // per-lane src offset in a chunk

  // Issue 18 DMA loads (x,y used planes) for chunk i into buffer `buf`.
  auto issue = [&](int i, int buf) {
    const long goff = base0 + (long)i * CHUNK;
    float* dst = smem + buf * (18 * CHUNK);
#pragma unroll
    for (int q = 0; q < 9; ++q)
      dma16(x + (long)USED[q] * NF + goff + lsrc, dst + q * CHUNK + wv * 256);
#pragma unroll
    for (int q = 0; q < 9; ++q)
      dma16(y + (long)USED[q] * NF + goff + lsrc, dst + (9 + q) * CHUNK + wv * 256);
  };

  // Prologue: 2 chunks in flight; s prefetched in registers.
  issue(0, 0);
  float4 svC = *(const float4*)(out + base0 + tid * 4);
  asm volatile("" ::: "memory");  // keep chunk-0 ops before chunk-1 ops
  issue(1, 1);
  float4 svN = *(const float4*)(out + base0 + CHUNK + tid * 4);

  for (int i = 0; i < CPB; ++i) {
    const int cur = i & 1;
    // Wait for chunk i's 18 DMA + this chunk's s-load; leave the newest 19
    // vmem ops (next chunk's DMA + s) in flight.
    asm volatile("s_waitcnt vmcnt(19)" ::: "memory");

    const long goff = base0 + (long)i * CHUNK;
    const float* L = smem + cur * (18 * CHUNK);

    float4 xq[9], yq[9];
#pragma unroll
    for (int q = 0; q < 9; ++q) xq[q] = *(const float4*)(L + q * CHUNK + tid * 4);
#pragma unroll
    for (int q = 0; q < 9; ++q) yq[q] = *(const float4*)(L + (9 + q) * CHUNK + tid * 4);

    float4 acc[9];
#pragma unroll
    for (int q = 0; q < 9; ++q) acc[q] = make_float4(0.f, 0.f, 0.f, 0.f);

#pragma unroll
    for (int t = 0; t < NTERMS; ++t) {
      const int qo = ACC_IDX[TERMS[t].o];
      const int qa = ACC_IDX[TERMS[t].a];
      const int qb = ACC_IDX[TERMS[t].b];
      const float c = d2s[t];
      acc[qo].x = fmaf(c, xq[qa].x * yq[qb].x, acc[qo].x);
      acc[qo].y = fmaf(c, xq[qa].y * yq[qb].y, acc[qo].y);
      acc[qo].z = fmaf(c, xq[qa].z * yq[qb].z, acc[qo].z);
      acc[qo].w = fmaf(c, xq[qa].w * yq[qb].w, acc[qo].w);
    }

#pragma unroll
    for (int o = 0; o < 15; ++o) {
      const int q = ACC_IDX[o];
      float4 r;
      if (q >= 0) {
        r.x = acc[q].x * svC.x;
        r.y = acc[q].y * svC.y;
        r.z = acc[q].z * svC.z;
        r.w = acc[q].w * svC.w;
      } else {
        r = make_float4(0.f, 0.f, 0.f, 0.f);
      }
      *(float4*)(out + (long)o * NF + goff + tid * 4) = r;
    }

    svC = svN;
    if (i + 2 < CPB) {
      issue(i + 2, cur);  // reuse the buffer just consumed
      svN = *(const float4*)(out + goff + 2 * CHUNK + tid * 4);
    }
  }
}

}  // namespace

extern "C" void kernel_launch(void* const* d_in, const int* in_sizes, int n_in,
                              void* d_out, int out_size, void* d_ws, size_t ws_size,
                              hipStream_t stream) {
  const float* x = (const float*)d_in[0];
  const float* y = (const float*)d_in[1];
  const float* g = (const float*)d_in[2];
  const float* w1 = (const float*)d_in[3];
  const float* w2 = (const float*)d_in[4];
  const float* cg = (const float*)d_in[5];
  float* out = (float*)d_out;

  // Pass 1: s[n,f] -> plane 0 of out (a guaranteed-zero output plane).
  s_kernel<<<1250, 256, 0, stream>>>(g, w1, w2, out);
  // Pass 2: DMA-pipelined streaming contraction; writes all 15 planes.
  const size_t shmem = (size_t)(2 * 18 * CHUNK + 128) * sizeof(float);
  tp_kernel<<<BLOCKS, 256, shmem, stream>>>(x, y, cg, out);
}

// Round 7
// 216.001 us; speedup vs baseline: 1.7451x; 1.0225x over previous
//
#include <hip/hip_runtime.h>
#include <array>

namespace {

constexpr int NPAIRS = 40000;
constexpr long NF = (long)NPAIRS * 128;  // elements per (l,m) plane

// ---------------------------------------------------------------------------
// Compile-time enumeration of nonzero CG terms (symmetrized):
// out[o] += (cg[o,a,b]+cg[o,b,a]) * x[a] * y[b]
// ---------------------------------------------------------------------------
struct Term {
  int o, a, b;
};

constexpr int count_terms() {
  int idx = 0;
  for (int o = 0; o < 15; ++o) {
    const int l3 = o / 5, m3 = o % 5 - 2;
    if (m3 < -l3 || m3 > l3) continue;
    for (int l1 = 0; l1 < 3; ++l1)
      for (int l2 = 0; l2 < 3; ++l2) {
        const int ld = l1 > l2 ? l1 - l2 : l2 - l1;
        if (l3 < ld || l3 > l1 + l2) continue;
        const int mlo = (-l1 > m3 - l2) ? -l1 : m3 - l2;
        const int mhi = (l1 < m3 + l2) ? l1 : m3 + l2;
        for (int m1 = mlo; m1 <= mhi; ++m1) ++idx;
      }
  }
  return idx;
}
constexpr int NTERMS = count_terms();
static_assert(NTERMS == 117, "term count");

constexpr std::array<Term, NTERMS> make_terms() {
  std::array<Term, NTERMS> t{};
  int idx = 0;
  for (int o = 0; o < 15; ++o) {
    const int l3 = o / 5, m3 = o % 5 - 2;
    if (m3 < -l3 || m3 > l3) continue;
    for (int l1 = 0; l1 < 3; ++l1)
      for (int l2 = 0; l2 < 3; ++l2) {
        const int ld = l1 > l2 ? l1 - l2 : l2 - l1;
        if (l3 < ld || l3 > l1 + l2) continue;
        const int mlo = (-l1 > m3 - l2) ? -l1 : m3 - l2;
        const int mhi = (l1 < m3 + l2) ? l1 : m3 + l2;
        for (int m1 = mlo; m1 <= mhi; ++m1) {
          t[idx].o = o;
          t[idx].a = l1 * 5 + m1 + 2;
          t[idx].b = l2 * 5 + (m3 - m1) + 2;
          ++idx;
        }
      }
  }
  return t;
}
constexpr auto TERMS = make_terms();

// Plane -> dense index for the 9 valid (l,m) slots; -1 for the 6 zero slots.
constexpr std::array<int, 15> make_acc_idx() {
  std::array<int, 15> m{};
  for (int o = 0; o < 15; ++o) m[o] = -1;
  int q = 0;
  for (int o = 0; o < 15; ++o) {
    const int l3 = o / 5, m3 = o % 5 - 2;
    if (m3 >= -l3 && m3 <= l3) m[o] = q++;
  }
  return m;
}
constexpr auto ACC_IDX = make_acc_idx();

constexpr std::array<int, 9> make_used() {
  std::array<int, 9> u{};
  int q = 0;
  for (int o = 0; o < 15; ++o)
    if (ACC_IDX[o] >= 0) u[q++] = o;
  return u;
}
constexpr auto USED = make_used();  // {2,6,7,8,10,11,12,13,14}

// The 6 identically-zero output planes.
__constant__ constexpr int ZPLANES[6] = {0, 1, 3, 4, 5, 9};

// ---------------------------------------------------------------------------
// Kernel A: s[n,f] = (w1 h)(w2 h) -> s_out; ALSO zero-fills the zero output
// planes (its memory pipe is otherwise idle during the GEMM).
// zstart: 0 = zero all 6 planes (s in workspace); 1 = skip plane 0 (s lives
// in plane 0 of out; tp zeroes it after reading).
// ---------------------------------------------------------------------------
__global__ __launch_bounds__(256, 4) void s_kernel(const float* __restrict__ g,
                                                   const float* __restrict__ w1,
                                                   const float* __restrict__ w2,
                                                   float* __restrict__ s_out,
                                                   float* __restrict__ out,
                                                   int zstart) {
  __shared__ float ht[128][32];
  __shared__ float wt1[16][132];
  __shared__ float wt2[16][132];

  const int tid = threadIdx.x;
  const int blk = blockIdx.x;

  if (tid < 32) {
    const float gv = g[blk * 32 + tid];
    float hkm1 = 0.75112554446494248286f * expf(-0.5f * gv * gv);
    float hk = 1.41421356237309504880f * gv * hkm1;
    ht[0][tid] = hkm1;
    ht[1][tid] = hk;
#pragma unroll 1
    for (int k = 1; k <= 126; ++k) {
      const float kf = (float)k;
      const float hkp1 =
          sqrtf(2.0f / (kf + 1.0f)) * gv * hk - sqrtf(kf / (kf + 1.0f)) * hkm1;
      ht[k + 1][tid] = hkp1;
      hkm1 = hk;
      hk = hkp1;
    }
  }

  // Zero-fill the zero output planes (overlaps the GEMM below; memory pipe
  // is idle there). 1,280,000 float4 per plane / 320,000 threads = 4 each.
  {
    const long idx = (long)blk * 256 + tid;
    const float4 z = make_float4(0.f, 0.f, 0.f, 0.f);
    for (int zp = zstart; zp < 6; ++zp) {
      float* base = out + (long)ZPLANES[zp] * NF;
#pragma unroll
      for (int r = 0; r < 4; ++r)
        *(float4*)(base + (r * 320000 + idx) * 4) = z;
    }
  }

  const int fg = tid & 31;
  const int ng = tid >> 5;

  float acc1[4][4];
  float acc2[4][4];
#pragma unroll
  for (int i = 0; i < 4; ++i)
#pragma unroll
    for (int j = 0; j < 4; ++j) {
      acc1[i][j] = 0.f;
      acc2[i][j] = 0.f;
    }

  for (int kc = 0; kc < 8; ++kc) {
#pragma unroll
    for (int it = 0; it < 2; ++it) {
      const int lin = tid + it * 256;
      const int f = lin >> 2;
      const int kq = lin & 3;
      const float4 v1 = *(const float4*)(w1 + f * 128 + kc * 16 + kq * 4);
      const float4 v2 = *(const float4*)(w2 + f * 128 + kc * 16 + kq * 4);
      wt1[kq * 4 + 0][f] = v1.x;
      wt1[kq * 4 + 1][f] = v1.y;
      wt1[kq * 4 + 2][f] = v1.z;
      wt1[kq * 4 + 3][f] = v1.w;
      wt2[kq * 4 + 0][f] = v2.x;
      wt2[kq * 4 + 1][f] = v2.y;
      wt2[kq * 4 + 2][f] = v2.z;
      wt2[kq * 4 + 3][f] = v2.w;
    }
    __syncthreads();

#pragma unroll
    for (int kk = 0; kk < 16; ++kk) {
      const float4 wv1 = *(const float4*)&wt1[kk][fg * 4];
      const float4 wv2 = *(const float4*)&wt2[kk][fg * 4];
      const float4 ha = *(const float4*)&ht[kc * 16 + kk][ng * 4];
      const float hv[4] = {ha.x, ha.y, ha.z, ha.w};
#pragma unroll
      for (int i = 0; i < 4; ++i) {
        acc1[i][0] = fmaf(hv[i], wv1.x, acc1[i][0]);
        acc1[i][1] = fmaf(hv[i], wv1.y, acc1[i][1]);
        acc1[i][2] = fmaf(hv[i], wv1.z, acc1[i][2]);
        acc1[i][3] = fmaf(hv[i], wv1.w, acc1[i][3]);
        acc2[i][0] = fmaf(hv[i], wv2.x, acc2[i][0]);
        acc2[i][1] = fmaf(hv[i], wv2.y, acc2[i][1]);
        acc2[i][2] = fmaf(hv[i], wv2.z, acc2[i][2]);
        acc2[i][3] = fmaf(hv[i], wv2.w, acc2[i][3]);
      }
    }
    __syncthreads();
  }

#pragma unroll
  for (int i = 0; i < 4; ++i) {
    const long n = (long)blk * 32 + ng * 4 + i;
    float4 sv;
    sv.x = acc1[i][0] * acc2[i][0];
    sv.y = acc1[i][1] * acc2[i][1];
    sv.z = acc1[i][2] * acc2[i][2];
    sv.w = acc1[i][3] * acc2[i][3];
    *(float4*)(s_out + n * 128 + fg * 4) = sv;
  }
}

// ---------------------------------------------------------------------------
// Kernel B: out[o,n,f] = s[n,f] * sum_t d2[t] x[a_t,n,f] y[b_t,n,f]
// Writes ONLY the 9 nonzero planes (zero planes handled by s_kernel).
// waves_per_eu(2,4): ~128-reg budget so all 19 loads batch without spill.
// zero_p0: 1 when s lives in plane 0 of out (ws too small) -> zero it here.
// ---------------------------------------------------------------------------
__global__ __attribute__((amdgpu_waves_per_eu(2, 4)))
__launch_bounds__(256) void tp_kernel(const float* __restrict__ x,
                                      const float* __restrict__ y,
                                      const float* __restrict__ cg,
                                      const float* __restrict__ s_in,
                                      float* __restrict__ out,
                                      int zero_p0) {
  __shared__ float d2s[NTERMS];
  const int tid = threadIdx.x;
  if (tid < NTERMS) {
    const Term tm = TERMS[tid];
    d2s[tid] = cg[(tm.o * 15 + tm.a) * 15 + tm.b] + cg[(tm.o * 15 + tm.b) * 15 + tm.a];
  }
  __syncthreads();

  const long off = (long)blockIdx.x * 1024 + tid * 4;

  float4 xv[9], yv[9];
#pragma unroll
  for (int q = 0; q < 9; ++q) xv[q] = *(const float4*)(x + (long)USED[q] * NF + off);
#pragma unroll
  for (int q = 0; q < 9; ++q) yv[q] = *(const float4*)(y + (long)USED[q] * NF + off);
  const float4 sv = *(const float4*)(s_in + off);

  float4 acc[9];
#pragma unroll
  for (int q = 0; q < 9; ++q) acc[q] = make_float4(0.f, 0.f, 0.f, 0.f);

#pragma unroll
  for (int t = 0; t < NTERMS; ++t) {
    const int qo = ACC_IDX[TERMS[t].o];
    const int qa = ACC_IDX[TERMS[t].a];
    const int qb = ACC_IDX[TERMS[t].b];
    const float c = d2s[t];
    acc[qo].x = fmaf(c, xv[qa].x * yv[qb].x, acc[qo].x);
    acc[qo].y = fmaf(c, xv[qa].y * yv[qb].y, acc[qo].y);
    acc[qo].z = fmaf(c, xv[qa].z * yv[qb].z, acc[qo].z);
    acc[qo].w = fmaf(c, xv[qa].w * yv[qb].w, acc[qo].w);
  }

  // If s was staged in plane 0 of out, zero it now (sv already consumed:
  // the compiler's waitcnt for the FMA uses precedes these stores).
  if (zero_p0) {
    *(float4*)(out + off) = make_float4(0.f, 0.f, 0.f, 0.f);
  }

#pragma unroll
  for (int q = 0; q < 9; ++q) {
    float4 r;
    r.x = acc[q].x * sv.x;
    r.y = acc[q].y * sv.y;
    r.z = acc[q].z * sv.z;
    r.w = acc[q].w * sv.w;
    *(float4*)(out + (long)USED[q] * NF + off) = r;
  }
}

}  // namespace

extern "C" void kernel_launch(void* const* d_in, const int* in_sizes, int n_in,
                              void* d_out, int out_size, void* d_ws, size_t ws_size,
                              hipStream_t stream) {
  const float* x = (const float*)d_in[0];
  const float* y = (const float*)d_in[1];
  const float* g = (const float*)d_in[2];
  const float* w1 = (const float*)d_in[3];
  const float* w2 = (const float*)d_in[4];
  const float* cg = (const float*)d_in[5];
  float* out = (float*)d_out;

  const size_t s_bytes = (size_t)NF * sizeof(float);  // 20.48 MB
  const bool use_ws = ws_size >= s_bytes;
  float* s_buf = use_ws ? (float*)d_ws : out;  // fallback: plane 0 of out

  // Pass 1: s + zero-fill of the zero output planes.
  s_kernel<<<1250, 256, 0, stream>>>(g, w1, w2, s_buf, out, use_ws ? 0 : 1);
  // Pass 2: contraction; writes the 9 nonzero planes.
  tp_kernel<<<5000, 256, 0, stream>>>(x, y, cg, s_buf, out, use_ws ? 0 : 1);
}